// Round 11
// baseline (249.677 us; speedup 1.0000x reference)
//
#include <hip/hip_runtime.h>
#include <hip/hip_bf16.h>

#define VNUM 6890
#define KJ 24
#define NBETA 10
#define NPOSE 207
#define KPAD 224        // NPOSE padded to 7*32; cols 207..216 carry betas
#define BATCH 1024
#define N3 20670        // VNUM*3
#define NVG 431         // vertex groups of 16
#define NROWF 20688     // NVG*48 rows in pdTf

// d_out element offsets (f32 elements)
#define OUT_V  0
#define OUT_JT 21166080
#define OUT_J  21239808
#define OUT_RM 21313536

// ws offsets (float units), all 16B-aligned
#define WS_JVJSP 0                // float[4*792] = 3168 -> ends 3168
#define WS_ABFF  3168             // ushort[1024*512]   = 262144 f -> ends 265312
#define WS_WBFF  265312           // ushort[432*512]    = 110592 f -> ends 375904
#define WS_PFBF  375904           // ushort[64*7*512]   = 114688 f -> ends 490592
#define WS_PDTF  490592           // ushort[431*21*512] = 2317056 f -> ends 2807648

typedef unsigned short ushort;
typedef __attribute__((ext_vector_type(8))) short short8v;
typedef __attribute__((ext_vector_type(4))) float floatx4;

__device__ __forceinline__ ushort f2bfu(float x) {
  __hip_bfloat16 h = __float2bfloat16(x);
  union { __hip_bfloat16 h; ushort u; } cv; cv.h = h; return cv.u;
}

// ---------------------------------------------------------------------------
// Kernel 0 (merged prep): flat grid 2364 blocks x 256.
//  blocks 0..95    : jreg section, COALESCED q-major (lane q reads sd[v*30+q],
//                    8 v-rows/block, LDS reduce) -> JvJsP[chunk][792], no
//                    atomics/memset. (Old version: lane-per-vertex scalar sd
//                    reads = 120B lane stride = ~64 lines/instr, 96 blocks
//                    on 37% of CUs.)
//  blocks 96..2363 : transpose_pd section (identical logic to before; first
//                    864 also convert lbs_weights -> wbff).
// jreg and tp are mutually independent -> one launch, tp fills the machine
// while jreg runs; saves 2 launch gaps + the memset launch.
// ---------------------------------------------------------------------------
__global__ __launch_bounds__(256) void prep_kernel(
    const float* __restrict__ Jr, const float* __restrict__ vt,
    const float* __restrict__ sd, float* __restrict__ JvJsP,
    const float* __restrict__ pd, ushort* __restrict__ pdTf,
    const float* __restrict__ w, ushort* __restrict__ wbff) {
  const int blk = blockIdx.x;
  const int t = threadIdx.x;

  if (blk < 96) {
    // ---- jreg section: j = blk>>2, chunk = blk&3 ----
    __shared__ float red[8][36];
    const int j = blk >> 2, chunk = blk & 3;
    const int q = t & 31, vrow = t >> 5;            // 8 v-rows
    const int vbeg = chunk * 1723;
    const int vend = (vbeg + 1723 < VNUM) ? vbeg + 1723 : VNUM;
    float accS = 0.0f, accV = 0.0f;
    for (int v = vbeg + vrow; v < vend; v += 8) {
      float r = Jr[j * VNUM + v];                   // broadcast within group
      if (q < 30) accS += r * sd[(size_t)v * 30 + q];   // coalesced
      if (q < 3)  accV += r * vt[(size_t)v * 3 + q];    // coalesced
    }
    red[vrow][(q < 30) ? (3 + q) : (33 + (q - 30))] = accS;
    if (q < 3) red[vrow][q] = accV;
    __syncthreads();
    if (t < 33) {
      float s = 0.0f;
#pragma unroll
      for (int rr = 0; rr < 8; rr++) s += red[rr][t];
      JvJsP[chunk * 792 + j * 33 + t] = s;
    }
    return;
  }

  // ---- transpose_pd section ----
  const int bt = blk - 96;
  if (bt < 864) {                                   // wbff side-job
    int i = bt * 256 + t;
    int vg = i >> 9, e = i & 511;
    int quad = e >> 7, l15 = (e >> 3) & 15, jj = e & 7;
    int v = vg * 16 + l15, k = quad * 8 + jj;
    float x = (v < VNUM && k < 24) ? w[v * 24 + k] : 0.0f;
    wbff[i] = f2bfu(x);
  }
  __shared__ float tile[32][65];
  const int bx = bt % 324, by = bt / 324;
  const int n0 = bx * 64;
  const int k0 = by * 32;
  const int c = t & 63;
  for (int r = t >> 6; r < 32; r += 4) {
    int k = k0 + r, n = n0 + c;
    float x = 0.0f;
    if (n < N3) {
      if (k < NPOSE) x = pd[(size_t)k * N3 + n];
      else if (k < NPOSE + NBETA) x = sd[(size_t)n * 10 + (k - NPOSE)];
    }
    tile[r][c] = x;
  }
  __syncthreads();
  const int n = t >> 2;               // local row 0..63
  const int j0 = (t & 3) * 8;         // k offset within 32
  const int rg = n0 + n;              // global row
  if (rg >= NROWF) return;
  unsigned int outw[4];
#pragma unroll
  for (int jj = 0; jj < 4; jj++) {
    unsigned int lo = f2bfu(tile[j0 + jj * 2][n]);
    unsigned int hi = f2bfu(tile[j0 + jj * 2 + 1][n]);
    outw[jj] = lo | (hi << 16);
  }
  const int vg = rg / 48;
  const int rl = rg - vg * 48;
  const int ns = rl >> 4, l15 = rl & 15;
  const int kb = k0 >> 5, quad = j0 >> 3;
  *(uint4*)&pdTf[(size_t)(((vg * 3 + ns) * 7 + kb) * 512) + (quad * 16 + l15) * 8] =
      make_uint4(outw[0], outw[1], outw[2], outw[3]);
}

// ---------------------------------------------------------------------------
// Kernel 1: per-batch: rodrigues, joints_t, chain; writes FRAGMENT-MAJOR
// pfbf[(b>>4)*7+kb][lane*8] (lane=quad*16+(b&15)) and Abff[b][lane*8]
// (lane=quad*16+n, k=quad*8+j, n=12..15 zero).
// JvJs now read as 4 partial sums (JvJsP) folded into LDS once.
// ---------------------------------------------------------------------------
__global__ __launch_bounds__(64) void batch_prep(
    const float* __restrict__ body_pose, const float* __restrict__ betas,
    const float* __restrict__ global_orient, const float* __restrict__ JvJsP,
    float* __restrict__ out_jt, float* __restrict__ out_j, float* __restrict__ out_rm,
    ushort* __restrict__ pfbf, ushort* __restrict__ Abff) {
  const int b = blockIdx.x;
  const int t = threadIdx.x;
  __shared__ float JvJsS[792];
  __shared__ float R[24][9];
  __shared__ float jt[24][3];
  __shared__ float chR[24][9];
  __shared__ float cht[24][3];

  for (int i = t; i < 792; i += 64)
    JvJsS[i] = JvJsP[i] + JvJsP[792 + i] + JvJsP[1584 + i] + JvJsP[2376 + i];

  if (t < 24) {
    float ax, ay, az;
    if (t == 0) {
      ax = global_orient[b * 3 + 0];
      ay = global_orient[b * 3 + 1];
      az = global_orient[b * 3 + 2];
    } else {
      const float* p = body_pose + (size_t)b * 69 + (t - 1) * 3;
      ax = p[0]; ay = p[1]; az = p[2];
    }
    float px = ax + 1e-8f, py = ay + 1e-8f, pz = az + 1e-8f;
    float angle = sqrtf(px * px + py * py + pz * pz);
    float inv = 1.0f / angle;
    float rx = ax * inv, ry = ay * inv, rz = az * inv;
    float s = sinf(angle), c = cosf(angle);
    float cc = 1.0f - c;
    float m[9];
    m[0] = 1.0f - cc * (ry * ry + rz * rz);
    m[1] = -s * rz + cc * rx * ry;
    m[2] =  s * ry + cc * rx * rz;
    m[3] =  s * rz + cc * rx * ry;
    m[4] = 1.0f - cc * (rx * rx + rz * rz);
    m[5] = -s * rx + cc * ry * rz;
    m[6] = -s * ry + cc * rx * rz;
    m[7] =  s * rx + cc * ry * rz;
    m[8] = 1.0f - cc * (rx * rx + ry * ry);
#pragma unroll
    for (int e = 0; e < 9; e++) {
      R[t][e] = m[e];
      out_rm[(size_t)b * 216 + t * 9 + e] = m[e];
    }
  }
  __syncthreads();   // JvJsS ready (and R, used after next sync anyway)
  for (int idx = t; idx < 72; idx += 64) {
    int j = idx / 3, c = idx % 3;
    const float* JJ = JvJsS + j * 33;
    float s = JJ[c];
    const float* be = betas + (size_t)b * NBETA;
#pragma unroll
    for (int l = 0; l < NBETA; l++) s += be[l] * JJ[3 + c * 10 + l];
    jt[j][c] = s;
    out_jt[(size_t)b * 72 + idx] = s;
  }
  __syncthreads();
  // pose-feature fragment write: k = mI, dst lane = quad*16 + (b&15)
  for (int mI = t; mI < KPAD; mI += 64) {
    float val = 0.0f;
    if (mI < NPOSE) {
      int k = 1 + mI / 9, e = mI % 9;
      val = R[k][e] - ((e == 0 || e == 4 || e == 8) ? 1.0f : 0.0f);
    } else if (mI < NPOSE + NBETA) {
      val = betas[(size_t)b * NBETA + (mI - NPOSE)];
    }
    int kb = mI >> 5, quad = (mI >> 3) & 3, j = mI & 7;
    pfbf[(size_t)(((b >> 4) * 7 + kb) * 512) + (quad * 16 + (b & 15)) * 8 + j] =
        f2bfu(val);
  }
  if (t == 0) {
    const int par[24] = {-1, 0, 0, 0, 1, 2, 3, 4, 5, 6, 7, 8, 9, 9, 9, 12, 13, 14, 16, 17, 18, 19, 20, 21};
#pragma unroll
    for (int e = 0; e < 9; e++) chR[0][e] = R[0][e];
    cht[0][0] = jt[0][0]; cht[0][1] = jt[0][1]; cht[0][2] = jt[0][2];
    for (int k = 1; k < 24; k++) {
      int p = par[k];
      float rel0 = jt[k][0] - jt[p][0];
      float rel1 = jt[k][1] - jt[p][1];
      float rel2 = jt[k][2] - jt[p][2];
#pragma unroll
      for (int i = 0; i < 3; i++) {
        float a0 = chR[p][i * 3 + 0], a1 = chR[p][i * 3 + 1], a2 = chR[p][i * 3 + 2];
        chR[k][i * 3 + 0] = a0 * R[k][0] + a1 * R[k][3] + a2 * R[k][6];
        chR[k][i * 3 + 1] = a0 * R[k][1] + a1 * R[k][4] + a2 * R[k][7];
        chR[k][i * 3 + 2] = a0 * R[k][2] + a1 * R[k][5] + a2 * R[k][8];
        cht[k][i] = a0 * rel0 + a1 * rel1 + a2 * rel2 + cht[p][i];
      }
    }
  }
  __syncthreads();
  if (t < 24) {
    int k = t;
#pragma unroll
    for (int i = 0; i < 3; i++) out_j[(size_t)b * 72 + k * 3 + i] = cht[k][i];
  }
  // Abff[b*512 + e]: e = (quad*16+n)*8+j, k = quad*8+j; n>=12 or k>=24 -> 0
  for (int e = t; e < 512; e += 64) {
    int quad = e >> 7, n = (e >> 3) & 15, j = e & 7;
    int k = quad * 8 + j;
    float val = 0.0f;
    if (n < 12 && k < 24) {
      int i = n >> 2, jj = n & 3;
      if (jj < 3) {
        val = chR[k][i * 3 + jj];
      } else {
        val = cht[k][i] - (chR[k][i * 3 + 0] * jt[k][0] +
                           chR[k][i * 3 + 1] * jt[k][1] +
                           chR[k][i * 3 + 2] * jt[k][2]);
      }
    }
    Abff[(size_t)b * 512 + e] = f2bfu(val);
  }
}

// ---------------------------------------------------------------------------
// Kernel 2 (fused, v7 — unchanged from R10, validated −15 µs):
// wave = 8 batches x ALL 4 vgs in phase 2; each Abff fragment loaded once
// and feeds 4 MFMAs; vpS per-vertex float4 rows (stride 68); one barrier.
// ---------------------------------------------------------------------------
__global__ __launch_bounds__(256, 4) void fused_mfma(
    const ushort* __restrict__ pfbf, const ushort* __restrict__ pdTf,
    const float* __restrict__ vt, const ushort* __restrict__ wbff,
    const ushort* __restrict__ Abff, float* __restrict__ out_v) {
  __shared__ float vpS[4 * 32 * 68];               // 34816 B
  const int tid = threadIdx.x;
  const int lane = tid & 63, wv = tid >> 6;        // 4 waves
  const int l15 = lane & 15, quad = lane >> 4;

  const int bid = blockIdx.x;                      // 3456 = 8*432
  const int L = (bid & 7) * 432 + (bid >> 3);
  const int bt = L & 31;                           // batch tile (fastest)
  const int q  = L >> 5;                           // vg-quad 0..107
  const int bm = bt * 32;                          // block's 32 batches
  const int vg = q * 4 + wv;                       // phase-1 vg of this wave
  const int vgc = (vg < NVG) ? vg : (NVG - 1);

  // wf for all 4 vgs of the block (phase 2); issued early
  short8v wf[4];
#pragma unroll
  for (int v4 = 0; v4 < 4; v4++) {
    int g = q * 4 + v4; if (g >= NVG) g = NVG - 1;
    wf[v4] = *(const short8v*)(wbff + (size_t)g * 512 + lane * 8);
  }
  const int gn0 = vgc * 48 + l15;
  float vt0 = (gn0      < N3) ? vt[gn0]      : 0.0f;
  float vt1 = (gn0 + 16 < N3) ? vt[gn0 + 16] : 0.0f;
  float vt2 = (gn0 + 32 < N3) ? vt[gn0 + 32] : 0.0f;

  // Phase 1: 2 batch-groups x own vg (48 cols); bpf shared across bgroups
  const ushort* apf0 = pfbf + (size_t)((bm >> 4) * 7) * 512 + lane * 8;
  const ushort* apf1 = apf0 + 7 * 512;
  const ushort* bpf  = pdTf + (size_t)(vgc * 21) * 512 + lane * 8;

  const floatx4 zero = {0.0f, 0.0f, 0.0f, 0.0f};
  floatx4 acc[2][3];
#pragma unroll
  for (int bg = 0; bg < 2; bg++)
#pragma unroll
    for (int ns = 0; ns < 3; ns++) acc[bg][ns] = zero;

#pragma unroll
  for (int kb = 0; kb < 7; kb++) {
    short8v a0 = *(const short8v*)(apf0 + kb * 512);
    short8v a1 = *(const short8v*)(apf1 + kb * 512);
    short8v b0 = *(const short8v*)(bpf + (0 * 7 + kb) * 512);
    short8v b1 = *(const short8v*)(bpf + (1 * 7 + kb) * 512);
    short8v b2 = *(const short8v*)(bpf + (2 * 7 + kb) * 512);
    acc[0][0] = __builtin_amdgcn_mfma_f32_16x16x32_bf16(a0, b0, acc[0][0], 0, 0, 0);
    acc[0][1] = __builtin_amdgcn_mfma_f32_16x16x32_bf16(a0, b1, acc[0][1], 0, 0, 0);
    acc[0][2] = __builtin_amdgcn_mfma_f32_16x16x32_bf16(a0, b2, acc[0][2], 0, 0, 0);
    acc[1][0] = __builtin_amdgcn_mfma_f32_16x16x32_bf16(a1, b0, acc[1][0], 0, 0, 0);
    acc[1][1] = __builtin_amdgcn_mfma_f32_16x16x32_bf16(a1, b1, acc[1][1], 0, 0, 0);
    acc[1][2] = __builtin_amdgcn_mfma_f32_16x16x32_bf16(a1, b2, acc[1][2], 0, 0, 0);
  }

  // vpS: per-vertex float4 layout [wv][b][v*4+c], row stride 68 floats
  float* myvp = vpS + wv * 2176;
  int v_[3], c_[3];
#pragma unroll
  for (int ns = 0; ns < 3; ns++) {
    int col = ns * 16 + l15;
    v_[ns] = col / 3;
    c_[ns] = col - v_[ns] * 3;
  }
#pragma unroll
  for (int bg = 0; bg < 2; bg++) {
#pragma unroll
    for (int r = 0; r < 4; r++) {
      int row = bg * 16 + quad * 4 + r;
      myvp[row * 68 + v_[0] * 4 + c_[0]] = acc[bg][0][r] + vt0;
      myvp[row * 68 + v_[1] * 4 + c_[1]] = acc[bg][1][r] + vt1;
      myvp[row * 68 + v_[2] * 4 + c_[2]] = acc[bg][2][r] + vt2;
    }
  }

  // T14 issue-early: this wave's 8 A-fragments (used after the barrier)
  short8v apre[8];
  {
    const ushort* abase = Abff + (size_t)(bm + wv * 8) * 512 + lane * 8;
#pragma unroll
    for (int j = 0; j < 8; j++) apre[j] = *(const short8v*)(abase + j * 512);
  }

  __syncthreads();   // cross-wave vpS visibility

  // Phase 2: wave wv handles batches bm+wv*8..+7 across ALL 4 vgs
  bool act[4];
  int gvv[4];
#pragma unroll
  for (int v4 = 0; v4 < 4; v4++) {
    int vg2 = q * 4 + v4;
    gvv[v4] = vg2 * 16 + l15;
    act[v4] = (quad < 3) && (vg2 < NVG) && (gvv[v4] < VNUM);
  }

#pragma unroll
  for (int i = 0; i < 8; i++) {
    const int b = wv * 8 + i;
    const size_t gb = (size_t)(bm + b);
    short8v afrag = apre[i];
#pragma unroll
    for (int v4 = 0; v4 < 4; v4++) {
      floatx4 t = __builtin_amdgcn_mfma_f32_16x16x32_bf16(afrag, wf[v4], zero, 0, 0, 0);
      const float4 p = *(const float4*)&vpS[v4 * 2176 + b * 68 + l15 * 4];
      if (act[v4]) {
        out_v[gb * N3 + (size_t)gvv[v4] * 3 + quad] =
            t[0] * p.x + t[1] * p.y + t[2] * p.z + t[3];
      }
    }
  }
}

extern "C" void kernel_launch(void* const* d_in, const int* in_sizes, int n_in,
                              void* d_out, int out_size, void* d_ws, size_t ws_size,
                              hipStream_t stream) {
  const float* body_pose     = (const float*)d_in[0];
  const float* betas         = (const float*)d_in[1];
  const float* global_orient = (const float*)d_in[2];
  const float* v_template    = (const float*)d_in[3];
  const float* shapedirs     = (const float*)d_in[4];
  const float* posedirs      = (const float*)d_in[5];
  const float* J_regressor   = (const float*)d_in[6];
  const float* lbs_weights   = (const float*)d_in[7];

  float* out = (float*)d_out;
  float* out_v  = out + OUT_V;
  float* out_jt = out + OUT_JT;
  float* out_j  = out + OUT_J;
  float* out_rm = out + OUT_RM;

  float* ws = (float*)d_ws;
  float* JvJsP = ws + WS_JVJSP;
  ushort* Abff = (ushort*)(ws + WS_ABFF);
  ushort* wbff = (ushort*)(ws + WS_WBFF);
  ushort* pfbf = (ushort*)(ws + WS_PFBF);
  ushort* pdTf = (ushort*)(ws + WS_PDTF);

  prep_kernel<<<2364, 256, 0, stream>>>(J_regressor, v_template, shapedirs,
                                        JvJsP, posedirs, pdTf, lbs_weights, wbff);
  batch_prep<<<BATCH, 64, 0, stream>>>(body_pose, betas, global_orient, JvJsP,
                                       out_jt, out_j, out_rm, pfbf, Abff);
  fused_mfma<<<3456, 256, 0, stream>>>(pfbf, pdTf, v_template, wbff, Abff, out_v);
}

// Round 12
// 179.409 us; speedup vs baseline: 1.3917x; 1.3917x over previous
//
#include <hip/hip_runtime.h>
#include <hip/hip_bf16.h>

#define VNUM 6890
#define KJ 24
#define NBETA 10
#define NPOSE 207
#define KPAD 224        // NPOSE padded to 7*32; cols 207..216 carry betas
#define BATCH 1024
#define N3 20670        // VNUM*3
#define NVG 431         // vertex groups of 16
#define NROWF 20688     // NVG*48 rows in pdTf

// d_out element offsets (f32 elements)
#define OUT_V  0
#define OUT_JT 21166080
#define OUT_J  21239808
#define OUT_RM 21313536

// ws offsets (float units), all 16B-aligned
#define WS_JVJSP 0                // float[4*792] = 3168 -> ends 3168
#define WS_ABFF  3168             // ushort[1024*512]   = 262144 f -> ends 265312
#define WS_WBFF  265312           // ushort[432*512]    = 110592 f -> ends 375904
#define WS_PFBF  375904           // ushort[64*7*512]   = 114688 f -> ends 490592
#define WS_PDTF  490592           // ushort[431*21*512] = 2317056 f -> ends 2807648

typedef unsigned short ushort;
typedef __attribute__((ext_vector_type(8))) short short8v;
typedef __attribute__((ext_vector_type(4))) float floatx4;

__device__ __forceinline__ ushort f2bfu(float x) {
  __hip_bfloat16 h = __float2bfloat16(x);
  union { __hip_bfloat16 h; ushort u; } cv; cv.h = h; return cv.u;
}

// ---------------------------------------------------------------------------
// Kernel 0 (merged prep): flat grid 2364 blocks x 256.
//  blocks 0..95    : jreg section — ORIGINAL lane-per-vertex algorithm
//                    (~7 iters/thread, acc[33] independent chains, shuffle+LDS
//                    reduce). R11's q-major rewrite collapsed it to one
//                    215-deep serial dep chain (99 µs) — ILP, not coalescing,
//                    was the binding resource. Writes JvJsP[chunk] partials
//                    (no atomics, no memset).
//  blocks 96..2363 : transpose_pd section (first 864 also convert
//                    lbs_weights -> wbff).
// ---------------------------------------------------------------------------
__global__ __launch_bounds__(256) void prep_kernel(
    const float* __restrict__ Jr, const float* __restrict__ vt,
    const float* __restrict__ sd, float* __restrict__ JvJsP,
    const float* __restrict__ pd, ushort* __restrict__ pdTf,
    const float* __restrict__ w, ushort* __restrict__ wbff) {
  const int blk = blockIdx.x;
  const int t = threadIdx.x;

  if (blk < 96) {
    // ---- jreg section (original algorithm): j = blk>>2, chunk = blk&3 ----
    __shared__ float red[4][33];
    const int j = blk >> 2, chunk = blk & 3;
    const int lane = t & 63, wid = t >> 6;
    const int vbeg = chunk * 1723;
    const int vend = (vbeg + 1723 < VNUM) ? vbeg + 1723 : VNUM;
    float acc[33];
#pragma unroll
    for (int q = 0; q < 33; q++) acc[q] = 0.0f;
    for (int v = vbeg + t; v < vend; v += 256) {
      float r = Jr[j * VNUM + v];
      const float* vtp = vt + v * 3;
      const float* sdp = sd + v * 30;
      acc[0] += r * vtp[0];
      acc[1] += r * vtp[1];
      acc[2] += r * vtp[2];
#pragma unroll
      for (int q = 0; q < 30; q++) acc[3 + q] += r * sdp[q];
    }
#pragma unroll
    for (int q = 0; q < 33; q++) {
      float x = acc[q];
      for (int off = 32; off > 0; off >>= 1) x += __shfl_down(x, off, 64);
      if (lane == 0) red[wid][q] = x;
    }
    __syncthreads();
    if (t < 33)
      JvJsP[chunk * 792 + j * 33 + t] =
          red[0][t] + red[1][t] + red[2][t] + red[3][t];
    return;
  }

  // ---- transpose_pd section ----
  const int bt = blk - 96;
  if (bt < 864) {                                   // wbff side-job
    int i = bt * 256 + t;
    int vg = i >> 9, e = i & 511;
    int quad = e >> 7, l15 = (e >> 3) & 15, jj = e & 7;
    int v = vg * 16 + l15, k = quad * 8 + jj;
    float x = (v < VNUM && k < 24) ? w[v * 24 + k] : 0.0f;
    wbff[i] = f2bfu(x);
  }
  __shared__ float tile[32][65];
  const int bx = bt % 324, by = bt / 324;
  const int n0 = bx * 64;
  const int k0 = by * 32;
  const int c = t & 63;
  for (int r = t >> 6; r < 32; r += 4) {
    int k = k0 + r, n = n0 + c;
    float x = 0.0f;
    if (n < N3) {
      if (k < NPOSE) x = pd[(size_t)k * N3 + n];
      else if (k < NPOSE + NBETA) x = sd[(size_t)n * 10 + (k - NPOSE)];
    }
    tile[r][c] = x;
  }
  __syncthreads();
  const int n = t >> 2;               // local row 0..63
  const int j0 = (t & 3) * 8;         // k offset within 32
  const int rg = n0 + n;              // global row
  if (rg >= NROWF) return;
  unsigned int outw[4];
#pragma unroll
  for (int jj = 0; jj < 4; jj++) {
    unsigned int lo = f2bfu(tile[j0 + jj * 2][n]);
    unsigned int hi = f2bfu(tile[j0 + jj * 2 + 1][n]);
    outw[jj] = lo | (hi << 16);
  }
  const int vg = rg / 48;
  const int rl = rg - vg * 48;
  const int ns = rl >> 4, l15 = rl & 15;
  const int kb = k0 >> 5, quad = j0 >> 3;
  *(uint4*)&pdTf[(size_t)(((vg * 3 + ns) * 7 + kb) * 512) + (quad * 16 + l15) * 8] =
      make_uint4(outw[0], outw[1], outw[2], outw[3]);
}

// ---------------------------------------------------------------------------
// Kernel 1: per-batch: rodrigues, joints_t, chain; writes FRAGMENT-MAJOR
// pfbf[(b>>4)*7+kb][lane*8] (lane=quad*16+(b&15)) and Abff[b][lane*8]
// (lane=quad*16+n, k=quad*8+j, n=12..15 zero).
// JvJs read as 4 partial sums (JvJsP) folded into LDS once.
// ---------------------------------------------------------------------------
__global__ __launch_bounds__(64) void batch_prep(
    const float* __restrict__ body_pose, const float* __restrict__ betas,
    const float* __restrict__ global_orient, const float* __restrict__ JvJsP,
    float* __restrict__ out_jt, float* __restrict__ out_j, float* __restrict__ out_rm,
    ushort* __restrict__ pfbf, ushort* __restrict__ Abff) {
  const int b = blockIdx.x;
  const int t = threadIdx.x;
  __shared__ float JvJsS[792];
  __shared__ float R[24][9];
  __shared__ float jt[24][3];
  __shared__ float chR[24][9];
  __shared__ float cht[24][3];

  for (int i = t; i < 792; i += 64)
    JvJsS[i] = JvJsP[i] + JvJsP[792 + i] + JvJsP[1584 + i] + JvJsP[2376 + i];

  if (t < 24) {
    float ax, ay, az;
    if (t == 0) {
      ax = global_orient[b * 3 + 0];
      ay = global_orient[b * 3 + 1];
      az = global_orient[b * 3 + 2];
    } else {
      const float* p = body_pose + (size_t)b * 69 + (t - 1) * 3;
      ax = p[0]; ay = p[1]; az = p[2];
    }
    float px = ax + 1e-8f, py = ay + 1e-8f, pz = az + 1e-8f;
    float angle = sqrtf(px * px + py * py + pz * pz);
    float inv = 1.0f / angle;
    float rx = ax * inv, ry = ay * inv, rz = az * inv;
    float s = sinf(angle), c = cosf(angle);
    float cc = 1.0f - c;
    float m[9];
    m[0] = 1.0f - cc * (ry * ry + rz * rz);
    m[1] = -s * rz + cc * rx * ry;
    m[2] =  s * ry + cc * rx * rz;
    m[3] =  s * rz + cc * rx * ry;
    m[4] = 1.0f - cc * (rx * rx + rz * rz);
    m[5] = -s * rx + cc * ry * rz;
    m[6] = -s * ry + cc * rx * rz;
    m[7] =  s * rx + cc * ry * rz;
    m[8] = 1.0f - cc * (rx * rx + ry * ry);
#pragma unroll
    for (int e = 0; e < 9; e++) {
      R[t][e] = m[e];
      out_rm[(size_t)b * 216 + t * 9 + e] = m[e];
    }
  }
  __syncthreads();   // JvJsS ready
  for (int idx = t; idx < 72; idx += 64) {
    int j = idx / 3, c = idx % 3;
    const float* JJ = JvJsS + j * 33;
    float s = JJ[c];
    const float* be = betas + (size_t)b * NBETA;
#pragma unroll
    for (int l = 0; l < NBETA; l++) s += be[l] * JJ[3 + c * 10 + l];
    jt[j][c] = s;
    out_jt[(size_t)b * 72 + idx] = s;
  }
  __syncthreads();
  // pose-feature fragment write: k = mI, dst lane = quad*16 + (b&15)
  for (int mI = t; mI < KPAD; mI += 64) {
    float val = 0.0f;
    if (mI < NPOSE) {
      int k = 1 + mI / 9, e = mI % 9;
      val = R[k][e] - ((e == 0 || e == 4 || e == 8) ? 1.0f : 0.0f);
    } else if (mI < NPOSE + NBETA) {
      val = betas[(size_t)b * NBETA + (mI - NPOSE)];
    }
    int kb = mI >> 5, quad = (mI >> 3) & 3, j = mI & 7;
    pfbf[(size_t)(((b >> 4) * 7 + kb) * 512) + (quad * 16 + (b & 15)) * 8 + j] =
        f2bfu(val);
  }
  if (t == 0) {
    const int par[24] = {-1, 0, 0, 0, 1, 2, 3, 4, 5, 6, 7, 8, 9, 9, 9, 12, 13, 14, 16, 17, 18, 19, 20, 21};
#pragma unroll
    for (int e = 0; e < 9; e++) chR[0][e] = R[0][e];
    cht[0][0] = jt[0][0]; cht[0][1] = jt[0][1]; cht[0][2] = jt[0][2];
    for (int k = 1; k < 24; k++) {
      int p = par[k];
      float rel0 = jt[k][0] - jt[p][0];
      float rel1 = jt[k][1] - jt[p][1];
      float rel2 = jt[k][2] - jt[p][2];
#pragma unroll
      for (int i = 0; i < 3; i++) {
        float a0 = chR[p][i * 3 + 0], a1 = chR[p][i * 3 + 1], a2 = chR[p][i * 3 + 2];
        chR[k][i * 3 + 0] = a0 * R[k][0] + a1 * R[k][3] + a2 * R[k][6];
        chR[k][i * 3 + 1] = a0 * R[k][1] + a1 * R[k][4] + a2 * R[k][7];
        chR[k][i * 3 + 2] = a0 * R[k][2] + a1 * R[k][5] + a2 * R[k][8];
        cht[k][i] = a0 * rel0 + a1 * rel1 + a2 * rel2 + cht[p][i];
      }
    }
  }
  __syncthreads();
  if (t < 24) {
    int k = t;
#pragma unroll
    for (int i = 0; i < 3; i++) out_j[(size_t)b * 72 + k * 3 + i] = cht[k][i];
  }
  // Abff[b*512 + e]: e = (quad*16+n)*8+j, k = quad*8+j; n>=12 or k>=24 -> 0
  for (int e = t; e < 512; e += 64) {
    int quad = e >> 7, n = (e >> 3) & 15, j = e & 7;
    int k = quad * 8 + j;
    float val = 0.0f;
    if (n < 12 && k < 24) {
      int i = n >> 2, jj = n & 3;
      if (jj < 3) {
        val = chR[k][i * 3 + jj];
      } else {
        val = cht[k][i] - (chR[k][i * 3 + 0] * jt[k][0] +
                           chR[k][i * 3 + 1] * jt[k][1] +
                           chR[k][i * 3 + 2] * jt[k][2]);
      }
    }
    Abff[(size_t)b * 512 + e] = f2bfu(val);
  }
}

// ---------------------------------------------------------------------------
// Kernel 2 (fused, v7 — unchanged, validated): wave = 8 batches x ALL 4 vgs
// in phase 2; each Abff fragment loaded once, feeds 4 MFMAs; vpS per-vertex
// float4 rows (stride 68); one barrier.
// ---------------------------------------------------------------------------
__global__ __launch_bounds__(256, 4) void fused_mfma(
    const ushort* __restrict__ pfbf, const ushort* __restrict__ pdTf,
    const float* __restrict__ vt, const ushort* __restrict__ wbff,
    const ushort* __restrict__ Abff, float* __restrict__ out_v) {
  __shared__ float vpS[4 * 32 * 68];               // 34816 B
  const int tid = threadIdx.x;
  const int lane = tid & 63, wv = tid >> 6;        // 4 waves
  const int l15 = lane & 15, quad = lane >> 4;

  const int bid = blockIdx.x;                      // 3456 = 8*432
  const int L = (bid & 7) * 432 + (bid >> 3);
  const int bt = L & 31;                           // batch tile (fastest)
  const int q  = L >> 5;                           // vg-quad 0..107
  const int bm = bt * 32;                          // block's 32 batches
  const int vg = q * 4 + wv;                       // phase-1 vg of this wave
  const int vgc = (vg < NVG) ? vg : (NVG - 1);

  // wf for all 4 vgs of the block (phase 2); issued early
  short8v wf[4];
#pragma unroll
  for (int v4 = 0; v4 < 4; v4++) {
    int g = q * 4 + v4; if (g >= NVG) g = NVG - 1;
    wf[v4] = *(const short8v*)(wbff + (size_t)g * 512 + lane * 8);
  }
  const int gn0 = vgc * 48 + l15;
  float vt0 = (gn0      < N3) ? vt[gn0]      : 0.0f;
  float vt1 = (gn0 + 16 < N3) ? vt[gn0 + 16] : 0.0f;
  float vt2 = (gn0 + 32 < N3) ? vt[gn0 + 32] : 0.0f;

  // Phase 1: 2 batch-groups x own vg (48 cols); bpf shared across bgroups
  const ushort* apf0 = pfbf + (size_t)((bm >> 4) * 7) * 512 + lane * 8;
  const ushort* apf1 = apf0 + 7 * 512;
  const ushort* bpf  = pdTf + (size_t)(vgc * 21) * 512 + lane * 8;

  const floatx4 zero = {0.0f, 0.0f, 0.0f, 0.0f};
  floatx4 acc[2][3];
#pragma unroll
  for (int bg = 0; bg < 2; bg++)
#pragma unroll
    for (int ns = 0; ns < 3; ns++) acc[bg][ns] = zero;

#pragma unroll
  for (int kb = 0; kb < 7; kb++) {
    short8v a0 = *(const short8v*)(apf0 + kb * 512);
    short8v a1 = *(const short8v*)(apf1 + kb * 512);
    short8v b0 = *(const short8v*)(bpf + (0 * 7 + kb) * 512);
    short8v b1 = *(const short8v*)(bpf + (1 * 7 + kb) * 512);
    short8v b2 = *(const short8v*)(bpf + (2 * 7 + kb) * 512);
    acc[0][0] = __builtin_amdgcn_mfma_f32_16x16x32_bf16(a0, b0, acc[0][0], 0, 0, 0);
    acc[0][1] = __builtin_amdgcn_mfma_f32_16x16x32_bf16(a0, b1, acc[0][1], 0, 0, 0);
    acc[0][2] = __builtin_amdgcn_mfma_f32_16x16x32_bf16(a0, b2, acc[0][2], 0, 0, 0);
    acc[1][0] = __builtin_amdgcn_mfma_f32_16x16x32_bf16(a1, b0, acc[1][0], 0, 0, 0);
    acc[1][1] = __builtin_amdgcn_mfma_f32_16x16x32_bf16(a1, b1, acc[1][1], 0, 0, 0);
    acc[1][2] = __builtin_amdgcn_mfma_f32_16x16x32_bf16(a1, b2, acc[1][2], 0, 0, 0);
  }

  // vpS: per-vertex float4 layout [wv][b][v*4+c], row stride 68 floats
  float* myvp = vpS + wv * 2176;
  int v_[3], c_[3];
#pragma unroll
  for (int ns = 0; ns < 3; ns++) {
    int col = ns * 16 + l15;
    v_[ns] = col / 3;
    c_[ns] = col - v_[ns] * 3;
  }
#pragma unroll
  for (int bg = 0; bg < 2; bg++) {
#pragma unroll
    for (int r = 0; r < 4; r++) {
      int row = bg * 16 + quad * 4 + r;
      myvp[row * 68 + v_[0] * 4 + c_[0]] = acc[bg][0][r] + vt0;
      myvp[row * 68 + v_[1] * 4 + c_[1]] = acc[bg][1][r] + vt1;
      myvp[row * 68 + v_[2] * 4 + c_[2]] = acc[bg][2][r] + vt2;
    }
  }

  // T14 issue-early: this wave's 8 A-fragments (used after the barrier)
  short8v apre[8];
  {
    const ushort* abase = Abff + (size_t)(bm + wv * 8) * 512 + lane * 8;
#pragma unroll
    for (int j = 0; j < 8; j++) apre[j] = *(const short8v*)(abase + j * 512);
  }

  __syncthreads();   // cross-wave vpS visibility

  // Phase 2: wave wv handles batches bm+wv*8..+7 across ALL 4 vgs
  bool act[4];
  int gvv[4];
#pragma unroll
  for (int v4 = 0; v4 < 4; v4++) {
    int vg2 = q * 4 + v4;
    gvv[v4] = vg2 * 16 + l15;
    act[v4] = (quad < 3) && (vg2 < NVG) && (gvv[v4] < VNUM);
  }

#pragma unroll
  for (int i = 0; i < 8; i++) {
    const int b = wv * 8 + i;
    const size_t gb = (size_t)(bm + b);
    short8v afrag = apre[i];
#pragma unroll
    for (int v4 = 0; v4 < 4; v4++) {
      floatx4 t = __builtin_amdgcn_mfma_f32_16x16x32_bf16(afrag, wf[v4], zero, 0, 0, 0);
      const float4 p = *(const float4*)&vpS[v4 * 2176 + b * 68 + l15 * 4];
      if (act[v4]) {
        out_v[gb * N3 + (size_t)gvv[v4] * 3 + quad] =
            t[0] * p.x + t[1] * p.y + t[2] * p.z + t[3];
      }
    }
  }
}

extern "C" void kernel_launch(void* const* d_in, const int* in_sizes, int n_in,
                              void* d_out, int out_size, void* d_ws, size_t ws_size,
                              hipStream_t stream) {
  const float* body_pose     = (const float*)d_in[0];
  const float* betas         = (const float*)d_in[1];
  const float* global_orient = (const float*)d_in[2];
  const float* v_template    = (const float*)d_in[3];
  const float* shapedirs     = (const float*)d_in[4];
  const float* posedirs      = (const float*)d_in[5];
  const float* J_regressor   = (const float*)d_in[6];
  const float* lbs_weights   = (const float*)d_in[7];

  float* out = (float*)d_out;
  float* out_v  = out + OUT_V;
  float* out_jt = out + OUT_JT;
  float* out_j  = out + OUT_J;
  float* out_rm = out + OUT_RM;

  float* ws = (float*)d_ws;
  float* JvJsP = ws + WS_JVJSP;
  ushort* Abff = (ushort*)(ws + WS_ABFF);
  ushort* wbff = (ushort*)(ws + WS_WBFF);
  ushort* pfbf = (ushort*)(ws + WS_PFBF);
  ushort* pdTf = (ushort*)(ws + WS_PDTF);

  prep_kernel<<<2364, 256, 0, stream>>>(J_regressor, v_template, shapedirs,
                                        JvJsP, posedirs, pdTf, lbs_weights, wbff);
  batch_prep<<<BATCH, 64, 0, stream>>>(body_pose, betas, global_orient, JvJsP,
                                       out_jt, out_j, out_rm, pfbf, Abff);
  fused_mfma<<<3456, 256, 0, stream>>>(pfbf, pdTf, v_template, wbff, Abff, out_v);
}